// Round 12
// baseline (754.541 us; speedup 1.0000x reference)
//
#include <hip/hip_runtime.h>
#include <cstdio>
#include <cmath>

#define NUM_WORDS 2048
#define NUM_CAND 8192
#define HIDDEN 768
#define FEAT 20
#define FFNN_DIM 1000
#define SPAN_DIM 2324
#define TOP_NUM 819
#define MSW 30
#define KP2 1024   // FFNN padded to x32
#define NP 1024    // padded N
#define PNP 3072   // P matrix padded N (3 segments of 1024)

// d_out layout (floats): [scores 8192][top_idx 819][top_starts 819][top_ends 819]
//                        [top_span_emb 819*2324][top_scores 819]
#define OUT_TOPIDX   (NUM_CAND)
#define OUT_TSTART   (NUM_CAND + TOP_NUM)
#define OUT_TEND     (NUM_CAND + 2*TOP_NUM)
#define OUT_TEMB     (NUM_CAND + 3*TOP_NUM)
#define OUT_TSCORE   (NUM_CAND + 3*TOP_NUM + TOP_NUM*SPAN_DIM)

typedef short short8 __attribute__((ext_vector_type(8)));
typedef float f32x4 __attribute__((ext_vector_type(4)));
typedef unsigned short u16x4 __attribute__((ext_vector_type(4)));

__device__ __forceinline__ unsigned short bf16_rne(float x) {
    unsigned int u = __float_as_uint(x);
    unsigned int r = u + 0x7FFFu + ((u >> 16) & 1u);
    return (unsigned short)(r >> 16);
}
__device__ __forceinline__ float bf16_to_f(unsigned short h) {
    return __uint_as_float(((unsigned int)h) << 16);
}
// 2-way split: v = s0 + s1 + r, |r| <= 2^-16 |v| (r21-verified: absmax unchanged)
__device__ __forceinline__ void store_split2(unsigned short* p0, unsigned short* p1,
                                             size_t off, float v) {
    unsigned short h0 = bf16_rne(v);
    float r1 = v - bf16_to_f(h0);
    p0[off] = h0;
    p1[off] = bf16_rne(r1);
}

// async 16B global->LDS (gfx950 global_load_lds_dwordx4). LDS dest must be
// wave-uniform base + lane*16 -> linear LDS; swizzle applied to the GLOBAL source.
__device__ __forceinline__ void gl_lds16(const unsigned short* g, unsigned short* l) {
    __builtin_amdgcn_global_load_lds(
        (const __attribute__((address_space(1))) unsigned short*)g,
        (__attribute__((address_space(3))) unsigned short*)l, 16, 0, 0);
}

// ---------------- head scores + doc 2-split convert (r23 fusion) ----------------
__global__ void head_kernel(const float* __restrict__ doc, const float* __restrict__ hw,
                            const float* __restrict__ hb, float* __restrict__ out,
                            int* __restrict__ hist,
                            unsigned short* __restrict__ d0, unsigned short* __restrict__ d1) {
    int t = threadIdx.x;
    if (blockIdx.x == 0) {
        for (int i = t; i < NUM_WORDS; i += 256) hist[i] = 0;
    }
    int base = blockIdx.x * 4 * HIDDEN;
    for (int i = t; i < 4 * HIDDEN; i += 256)
        store_split2(d0, d1, (size_t)base + i, doc[base + i]);
    int wave = t >> 6, lane = t & 63;
    int row = blockIdx.x * 4 + wave;
    if (row >= NUM_WORDS) return;
    float acc = 0.f;
    for (int h = lane; h < HIDDEN; h += 64) acc += doc[row * HIDDEN + h] * hw[h];
    for (int off = 32; off > 0; off >>= 1) acc += __shfl_down(acc, off);
    if (lane == 0) out[row] = acc + hb[0];
}

// ---------------- width prior ffnn [30,20]->[30] + T_w rows (r23 fusion) ----------------
__global__ void width_kernel(const float* __restrict__ x, const float* __restrict__ w1,
                             const float* __restrict__ b1, const float* __restrict__ w2,
                             const float* __restrict__ b2, const float* __restrict__ w3,
                             const float* __restrict__ b3, float* __restrict__ out,
                             const float* __restrict__ swe, const float* __restrict__ mw1,
                             float* __restrict__ tw) {
    __shared__ float xs[FEAT];
    __shared__ float h1s[FFNN_DIM];
    __shared__ float red[256];
    int r = blockIdx.x, t = threadIdx.x;
    if (t < FEAT) xs[t] = x[r * FEAT + t];
    __syncthreads();
    for (int j = t; j < FFNN_DIM; j += 256) {
        float acc = b1[j];
        for (int k = 0; k < FEAT; ++k) acc += xs[k] * w1[k * FFNN_DIM + j];
        h1s[j] = fmaxf(acc, 0.f);
    }
    __syncthreads();
    float partial = 0.f;
    for (int j = t; j < FFNN_DIM; j += 256) {
        float acc = b2[j];
        for (int k = 0; k < FFNN_DIM; ++k) acc += h1s[k] * w2[k * FFNN_DIM + j];
        partial += fmaxf(acc, 0.f) * w3[j];
    }
    red[t] = partial;
    __syncthreads();
    for (int s = 128; s > 0; s >>= 1) { if (t < s) red[t] += red[t + s]; __syncthreads(); }
    if (t == 0) out[r] = red[0] + b3[0];
    // T_w[r][1024] = span_width_emb[r] @ m_w1[1536:1556] (bit-identical to old tw_kernel)
    for (int n = t; n < NP; n += 256) {
        float acc = 0.f;
        if (n < FFNN_DIM) {
            for (int f = 0; f < FEAT; ++f)
                acc += swe[r * FEAT + f] * mw1[(size_t)(1536 + f) * FFNN_DIM + n];
        }
        tw[r * NP + n] = acc;
    }
}

// ---------------- attention weights per span: attn_g [8192][32] ----------------
// r25: 2 candidates per wave (32-lane segments); bit-exact vs the 64-wide form.
__global__ void attn_kernel(const float* __restrict__ head_s, const int* __restrict__ starts,
                            const int* __restrict__ ends, float* __restrict__ attn_g,
                            int* __restrict__ hist) {
    int c = blockIdx.x * 8 + (threadIdx.x >> 5);
    int w = threadIdx.x & 31;
    if (c >= NUM_CAND) return;
    int s = starts[c], e = ends[c];
    if (w == 0) atomicAdd(&hist[s], 1);
    int wid = e - s;
    float hsv = (w < MSW && w <= wid) ? head_s[s + w] : -INFINITY;
    float m = hsv;
    for (int off = 16; off > 0; off >>= 1) m = fmaxf(m, __shfl_down(m, off, 32));
    m = __shfl(m, 0, 32);
    float ex = (w < MSW && w <= wid) ? expf(hsv - m) : 0.f;
    float ssum = ex;
    for (int off = 16; off > 0; off >>= 1) ssum += __shfl_down(ssum, off, 32);
    ssum = __shfl(ssum, 0, 32);
    attn_g[c * 32 + w] = (w < MSW) ? (ex / ssum) : 0.f;
}

// ---------------- counting-sort permutation by start (scan + scatter, 1 block) ----------
// r26: also writes the exclusive bin-start offsets to global binoff (consumed by the
// binned combine). Order within a bin is atomic-timing-dependent but any order is
// correct (combine writes by original candidate id with identical arithmetic).
__global__ __launch_bounds__(256) void perm_kernel(const int* __restrict__ hist,
                                                   const int* __restrict__ starts,
                                                   int* __restrict__ perm,
                                                   int* __restrict__ binoff) {
    __shared__ int hoff[NUM_WORDS];
    __shared__ int wsum[4];
    int t = threadIdx.x, lane = t & 63, wv = t >> 6;
    int base = t * 8;
    int lh[8];
    int s0 = 0;
#pragma unroll
    for (int i = 0; i < 8; ++i) { lh[i] = hist[base + i]; s0 += lh[i]; }
    int sc = s0;
    for (int o = 1; o < 64; o <<= 1) { int v = __shfl_up(sc, o); if (lane >= o) sc += v; }
    if (lane == 63) wsum[wv] = sc;
    __syncthreads();
    int wbase = 0;
    for (int i = 0; i < wv; ++i) wbase += wsum[i];
    int run = wbase + sc - s0;  // exclusive prefix of this thread's 8 bins
#pragma unroll
    for (int i = 0; i < 8; ++i) { hoff[base + i] = run; binoff[base + i] = run; run += lh[i]; }
    __syncthreads();
    for (int c = t; c < NUM_CAND; c += 256) {
        int pos = atomicAdd(&hoff[starts[c]], 1);
        perm[pos] = c;
    }
}

// ---------------- Wc convert via LDS tile-transpose: coalesced both sides --------------
__global__ __launch_bounds__(256) void convert_wc(const float* __restrict__ w1,
                                                  unsigned short* __restrict__ q0,
                                                  unsigned short* __restrict__ q1) {
    __shared__ float tile[64][65];
    int kbase = blockIdx.x << 6;            // 0..704 (12 tiles over 768)
    int n2base = blockIdx.y << 6;           // 0..3008 (48 tiles over 3072)
    int seg = n2base >> 10;
    int nbase = n2base & 1023;
    int row0 = (seg == 0) ? 0 : ((seg == 1) ? HIDDEN : 1556);
    int t = threadIdx.x;
    int c = t & 63, r0 = t >> 6;
    for (int rr = 0; rr < 64; rr += 4) {
        int r = rr + r0;
        int n = nbase + c;
        tile[r][c] = (n < FFNN_DIM) ? w1[(size_t)(row0 + kbase + r) * FFNN_DIM + n] : 0.f;
    }
    __syncthreads();
    int kl = t & 63;
    for (int rr = 0; rr < 64; rr += 4) {
        int nl = rr + r0;
        store_split2(q0, q1, (size_t)(n2base + nl) * HIDDEN + kbase + kl, tile[kl][nl]);
    }
}

// ---------------- w2 convert+transpose via LDS tiles: m_w2[1000][1000] -> [1024][1024] ---
__global__ __launch_bounds__(256) void convert_wt(const float* __restrict__ w,
                                                  unsigned short* __restrict__ q0,
                                                  unsigned short* __restrict__ q1) {
    __shared__ float tile[64][65];
    int kbase = blockIdx.x << 6;            // 16 tiles over 1024
    int nbase = blockIdx.y << 6;            // 16 tiles over 1024
    int t = threadIdx.x;
    int c = t & 63, r0 = t >> 6;
    for (int rr = 0; rr < 64; rr += 4) {
        int r = rr + r0;
        int k = kbase + r, n = nbase + c;
        tile[r][c] = (k < FFNN_DIM && n < FFNN_DIM) ? w[(size_t)k * FFNN_DIM + n] : 0.f;
    }
    __syncthreads();
    int kl = t & 63;
    for (int rr = 0; rr < 64; rr += 4) {
        int nl = rr + r0;
        store_split2(q0, q1, (size_t)(nbase + nl) * KP2 + kbase + kl, tile[kl][nl]);
    }
}

// Stage one 128x64-bf16 tile (16KB) async into LDS. r24: BK=64. LDS layout row-major
// [128][64]; LDS slot s (8 bf16) of row r holds global kblk s^(r&7).
__device__ __forceinline__ void stage_tile64(const unsigned short* __restrict__ src,
                                             unsigned short* lds, int base_row, int Kp,
                                             int k0, int t) {
#pragma unroll
    for (int qi = 0; qi < 4; ++qi) {
        int u = qi * 256 + t;           // 0..1023
        int row = u >> 3;
        int slot = u & 7;
        int kblk = slot ^ (row & 7);
        const unsigned short* g = src + (size_t)(base_row + row) * Kp + k0 + kblk * 8;
        gl_lds16(g, lds + u * 8);
    }
}

// ---------------- 2-split 3-product MFMA GEMM (BK=64), fp32 out: P = doc @ Wc ---------
__global__ __launch_bounds__(256, 2) void gemm3p(
    const unsigned short* __restrict__ A0, const unsigned short* __restrict__ A1,
    const unsigned short* __restrict__ B0, const unsigned short* __restrict__ B1,
    float* __restrict__ C) {
    __shared__ unsigned short As0[128 * 64], As1[128 * 64];
    __shared__ unsigned short Bs0[128 * 64], Bs1[128 * 64];
    int t = threadIdx.x;
    int bid = blockIdx.x;
    int g = bid & 7, rr = bid >> 3;         // xcd-chunk g: n_tiles {g, g+8, g+16}
    int bm = (rr & 15) << 7;
    int bn = (g + 8 * (rr >> 4)) << 7;
    int lane = t & 63, wv = t >> 6;
    int wm = (wv >> 1) * 64, wn = (wv & 1) * 64;
    int lr = lane & 15, qq = lane >> 4;

    f32x4 acc[4][4] = {};

    for (int k0 = 0; k0 < HIDDEN; k0 += 64) {
        stage_tile64(A0, As0, bm, HIDDEN, k0, t);
        stage_tile64(A1, As1, bm, HIDDEN, k0, t);
        stage_tile64(B0, Bs0, bn, HIDDEN, k0, t);
        stage_tile64(B1, Bs1, bn, HIDDEN, k0, t);
        __syncthreads();
        short8 a0[2][4], a1[2][4];
#pragma unroll
        for (int i = 0; i < 4; ++i) {
            int ra = (wm + i * 16 + lr) * 64;
#pragma unroll
            for (int h = 0; h < 2; ++h) {
                int sl = ((h * 4 + qq) ^ (lr & 7)) * 8;
                a0[h][i] = *(const short8*)&As0[ra + sl];
                a1[h][i] = *(const short8*)&As1[ra + sl];
            }
        }
#pragma unroll
        for (int j = 0; j < 4; ++j) {
            int rb = (wn + j * 16 + lr) * 64;
            short8 b0[2], b1[2];
#pragma unroll
            for (int h = 0; h < 2; ++h) {
                int sl = ((h * 4 + qq) ^ (lr & 7)) * 8;
                b0[h] = *(const short8*)&Bs0[rb + sl];
                b1[h] = *(const short8*)&Bs1[rb + sl];
            }
#pragma unroll
            for (int i = 0; i < 4; ++i) {
#pragma unroll
                for (int h = 0; h < 2; ++h) {
                    acc[i][j] = __builtin_amdgcn_mfma_f32_16x16x32_bf16(a1[h][i], b0[h], acc[i][j], 0, 0, 0);
                    acc[i][j] = __builtin_amdgcn_mfma_f32_16x16x32_bf16(a0[h][i], b1[h], acc[i][j], 0, 0, 0);
                    acc[i][j] = __builtin_amdgcn_mfma_f32_16x16x32_bf16(a0[h][i], b0[h], acc[i][j], 0, 0, 0);
                }
            }
        }
        __syncthreads();
    }
#pragma unroll
    for (int i = 0; i < 4; ++i)
#pragma unroll
        for (int j = 0; j < 4; ++j)
#pragma unroll
            for (int r = 0; r < 4; ++r) {
                int m = bm + wm + i * 16 + qq * 4 + r;
                int n = bn + wn + j * 16 + lr;
                C[(size_t)m * PNP + n] = acc[i][j][r];
            }
}

// ---------------- binned combine: one block per start-bin (r26) ----------------
// All candidates of a bin share P_s[s] and their Pa windows (rows s..s+30) -> L1 reuse.
// Per-candidate arithmetic byte-identical to the r16-verified body (bit-exact).
// XCD chunking: block b -> s = (b&7)*256 + (b>>3), so each XCD owns a contiguous
// 256-start slice of P (~3.4MB, fits 4MB L2).
__global__ void combine_kernel(const float* __restrict__ P, const float* __restrict__ tw,
                               const float* __restrict__ attn_g, const float* __restrict__ b1,
                               const int* __restrict__ starts, const int* __restrict__ ends,
                               const int* __restrict__ perm, const int* __restrict__ binoff,
                               const int* __restrict__ hist,
                               unsigned short* __restrict__ h0, unsigned short* __restrict__ h1) {
    int b = blockIdx.x;
    int s_bin = ((b & 7) << 8) | (b >> 3);
    int beg = binoff[s_bin];
    int cnt = hist[s_bin];
    int t = threadIdx.x;
    __shared__ float at[MSW];
    for (int q = 0; q < cnt; ++q) {
        int c = perm[beg + q];
        int s = starts[c], e = ends[c];
        int wid = e - s;
        if (t < MSW) at[t] = attn_g[c * 32 + t];
        __syncthreads();
        int n0 = t * 4;
        size_t ho = (size_t)c * NP + n0;
        if (t < 250) {
            f32x4 acc = *(const f32x4*)&P[(size_t)s * PNP + n0];
            acc += *(const f32x4*)&P[(size_t)e * PNP + 1024 + n0];
            acc += *(const f32x4*)&tw[(size_t)wid * NP + n0];
            acc += *(const f32x4*)&b1[n0];
            const float* Pa = P + (size_t)s * PNP + 2048 + n0;
            for (int w = 0; w <= wid; ++w)
                acc += at[w] * *(const f32x4*)&Pa[(size_t)w * PNP];
            u16x4 q0, q1;
#pragma unroll
            for (int k = 0; k < 4; ++k) {
                float v = fmaxf(acc[k], 0.f);
                unsigned short x0 = bf16_rne(v);
                float r1 = v - bf16_to_f(x0);
                q0[k] = x0; q1[k] = bf16_rne(r1);
            }
            *(u16x4*)&h0[ho] = q0;
            *(u16x4*)&h1[ho] = q1;
        } else {
            u16x4 z = {0, 0, 0, 0};
            *(u16x4*)&h0[ho] = z;
            *(u16x4*)&h1[ho] = z;
        }
        __syncthreads();
    }
}

// ---------------- 2-split 3-product MFMA GEMM (BK=64, score fusion) ------------
__global__ __launch_bounds__(256, 2) void gemm3(
    const unsigned short* __restrict__ A0, const unsigned short* __restrict__ A1,
    const unsigned short* __restrict__ B0, const unsigned short* __restrict__ B1,
    const float* __restrict__ bias, int nreal, int Kp,
    const float* __restrict__ w3, float* __restrict__ partials) {
    __shared__ unsigned short As0[128 * 64], As1[128 * 64];
    __shared__ unsigned short Bs0[128 * 64], Bs1[128 * 64];
    int t = threadIdx.x;
    int bid = blockIdx.x;
    int bm = (bid >> 3) << 7;               // 64 M-tiles
    int bn = (bid & 7) << 7;                // 8 N-tiles; n ≡ bid (mod 8) -> per-XCD panel
    int lane = t & 63, wv = t >> 6;
    int wm = (wv >> 1) * 64, wn = (wv & 1) * 64;
    int lr = lane & 15, qq = lane >> 4;

    f32x4 acc[4][4] = {};

    for (int k0 = 0; k0 < Kp; k0 += 64) {
        stage_tile64(A0, As0, bm, Kp, k0, t);
        stage_tile64(A1, As1, bm, Kp, k0, t);
        stage_tile64(B0, Bs0, bn, Kp, k0, t);
        stage_tile64(B1, Bs1, bn, Kp, k0, t);
        __syncthreads();
        short8 a0[2][4], a1[2][4];
#pragma unroll
        for (int i = 0; i < 4; ++i) {
            int ra = (wm + i * 16 + lr) * 64;
#pragma unroll
            for (int h = 0; h < 2; ++h) {
                int sl = ((h * 4 + qq) ^ (lr & 7)) * 8;
                a0[h][i] = *(const short8*)&As0[ra + sl];
                a1[h][i] = *(const short8*)&As1[ra + sl];
            }
        }
#pragma unroll
        for (int j = 0; j < 4; ++j) {
            int rb = (wn + j * 16 + lr) * 64;
            short8 b0[2], b1[2];
#pragma unroll
            for (int h = 0; h < 2; ++h) {
                int sl = ((h * 4 + qq) ^ (lr & 7)) * 8;
                b0[h] = *(const short8*)&Bs0[rb + sl];
                b1[h] = *(const short8*)&Bs1[rb + sl];
            }
#pragma unroll
            for (int i = 0; i < 4; ++i) {
#pragma unroll
                for (int h = 0; h < 2; ++h) {
                    acc[i][j] = __builtin_amdgcn_mfma_f32_16x16x32_bf16(a1[h][i], b0[h], acc[i][j], 0, 0, 0);
                    acc[i][j] = __builtin_amdgcn_mfma_f32_16x16x32_bf16(a0[h][i], b1[h], acc[i][j], 0, 0, 0);
                    acc[i][j] = __builtin_amdgcn_mfma_f32_16x16x32_bf16(a0[h][i], b0[h], acc[i][j], 0, 0, 0);
                }
            }
        }
        __syncthreads();
    }

    int pid = ((bn >> 7) << 1) | (wn >> 6);  // 0..15
#pragma unroll
    for (int i = 0; i < 4; ++i)
#pragma unroll
        for (int r = 0; r < 4; ++r) {
            float p = 0.f;
#pragma unroll
            for (int j = 0; j < 4; ++j) {
                int n = bn + wn + j * 16 + lr;
                float v = acc[i][j][r] + (n < nreal ? bias[n] : 0.f);
                v = fmaxf(v, 0.f);
                p += v * (n < nreal ? w3[n] : 0.f);
            }
            p += __shfl_xor(p, 1);
            p += __shfl_xor(p, 2);
            p += __shfl_xor(p, 4);
            p += __shfl_xor(p, 8);
            if (lr == 0) {
                int m = bm + wm + i * 16 + qq * 4 + r;
                partials[(size_t)m * 16 + pid] = p;
            }
        }
}

// ---------------- deterministic score finalize ----------------
__global__ void score_final(const float* __restrict__ partials, const float* __restrict__ b3,
                            const float* __restrict__ width_s, const int* __restrict__ starts,
                            const int* __restrict__ ends, float* __restrict__ out) {
    int c = blockIdx.x * 256 + threadIdx.x;
    if (c >= NUM_CAND) return;
    float s = b3[0] + width_s[ends[c] - starts[c]];
#pragma unroll
    for (int p = 0; p < 16; ++p) s += partials[(size_t)c * 16 + p];
    out[c] = s;
}

// ---------------- exact counting rank-sort: 256 blocks ----------------
__global__ __launch_bounds__(256) void rank_kernel(const float* __restrict__ scores,
                                                   const int* __restrict__ starts,
                                                   const int* __restrict__ ends,
                                                   unsigned short* __restrict__ ord_g,
                                                   unsigned int* __restrict__ se_g) {
    __shared__ unsigned long long kk[NUM_CAND];  // 64 KB
    int t = threadIdx.x;
    for (int i = t; i < NUM_CAND; i += 256) {
        unsigned int b = __float_as_uint(scores[i]);
        unsigned int u = b ^ ((b & 0x80000000u) ? 0xFFFFFFFFu : 0x80000000u);
        unsigned int hi = ~u;
        kk[i] = ((unsigned long long)hi << 32) | (unsigned int)i;
    }
    __syncthreads();
    int c = blockIdx.x * 32 + (t >> 3);
    int seg = (t & 7) * 1024;
    int rot = (t & 7) * 2;
    unsigned long long mykey = kk[c];
    int cnt = 0;
    for (int ii = 0; ii < 1024; ++ii) {
        int i = seg + ((ii + rot) & 1023);
        cnt += (kk[i] < mykey) ? 1 : 0;
    }
    cnt += __shfl_xor(cnt, 1);
    cnt += __shfl_xor(cnt, 2);
    cnt += __shfl_xor(cnt, 4);
    if ((t & 7) == 0) {
        int idx = (int)(mykey & 0xFFFFFFFFull);
        int rank = cnt;
        ord_g[rank] = (unsigned short)idx;
        se_g[rank] = ((unsigned int)starts[idx] << 16) | (unsigned int)ends[idx];
    }
}

// ---------------- merged NMS + span-order sort + emit (r25) ----------------
// NMS decision path LOCKED at the r17-verified form (~292us; r13/r15/r18/r19/r20 all
// worse — cost is dependent-chain latency, structural). Do not restructure further.
__global__ __launch_bounds__(512, 1)
__attribute__((amdgpu_waves_per_eu(1, 2)))
void select_nms_post(const unsigned int* __restrict__ se_g,
                     const unsigned short* __restrict__ ord_g,
                     const float* __restrict__ scores,
                     const int* __restrict__ starts,
                     const int* __restrict__ ends,
                     float* __restrict__ out, int* __restrict__ top_idx_ws) {
    __shared__ unsigned int se_arr[NUM_CAND];    // 32 KB
    __shared__ unsigned int st[2 * NUM_WORDS];   // 16 KB
    __shared__ unsigned short sel_sh[1024];      //  2 KB
    __shared__ unsigned long long fkeys[1024];   //  8 KB
    __shared__ int count_sh;
    int t = threadIdx.x;

    {
        const uint4* src4 = (const uint4*)se_g;
        uint4* dst4 = (uint4*)se_arr;
        for (int i = t; i < NUM_CAND / 4; i += 512) dst4[i] = src4[i];
    }
    for (int i = t; i < 2 * NUM_WORDS; i += 512)
        st[i] = (i & 1) ? (unsigned int)NUM_WORDS : 0u;  // max_end+1=0, min_start=2048
    __syncthreads();

    if (t < 64) {
        int lane = t;
        const unsigned long long* stp = (const unsigned long long*)st;
        int count = 0;
        for (int c = 0; c < NUM_CAND / 64; ++c) {
            int ib = c * 64;
            unsigned int sev = se_arr[ib + lane];
            int s = (int)(sev >> 16), e = (int)(sev & 0xFFFFu);
            const unsigned long long* bp = stp + s;
            unsigned long long v[MSW];
#pragma unroll
            for (int w = 0; w < MSW; ++w) v[w] = bp[w];
            int me = (int)(unsigned int)v[0] - 1;
            bool crossedA = (s < e) && ((int)(unsigned int)(v[0] >> 32) < s);
            bool crossedB = false;
#pragma unroll
            for (int w = 1; w < MSW; ++w) {
                int j = s + w;
                bool in = (j <= e);
                int mej = (int)(unsigned int)v[w] - 1;
                int msj = (int)(unsigned int)(v[w] >> 32);
                bool hit = in && ((mej > e) || ((j < e) && (msj < s)));
                if (w & 1) crossedA = crossedA || hit;
                else       crossedB = crossedB || hit;
            }
            bool crossed = crossedA || crossedB;
            bool spec = !crossed && (me != e);

            // serial resolve — decision loop identical to the r2..r17-verified form
            int cbefore = count;
            unsigned long long window = ~0ull;
            unsigned int pend = 0u;
            int rk = 0, lcnt = 0;
            while (true) {
                unsigned long long b = __ballot(spec) & window;
                if (b == 0ull) break;
                int f = __ffsll((unsigned long long)b) - 1;
                unsigned int sef = __builtin_amdgcn_readlane(sev, (unsigned int)f);
                int sf = (int)(sef >> 16), ef = (int)(sef & 0xFFFFu);
                bool mine = (lane == lcnt);
                pend = mine ? sef : pend;
                rk = mine ? (ib + f) : rk;
                lcnt++;
                count++;
                if (count >= TOP_NUM) break;
                window &= (f >= 63) ? 0ull : (~0ull << (f + 1));
                if (lane > f) {
                    if (s == sf) me = max(me, ef);
                    crossed = crossed || ((s < sf) && (sf <= e) && (ef > e))
                                      || ((sf < s) && (s <= ef) && (ef < e));
                    spec = !crossed && (me != e);
                }
            }
            if (lane < lcnt) {
                int sf = (int)(pend >> 16), ef = (int)(pend & 0xFFFFu);
                sel_sh[cbefore + lane] = (unsigned short)rk;
                atomicMax(&st[2 * sf], (unsigned int)(ef + 1));
                atomicMin(&st[2 * ef + 1], (unsigned int)sf);
            }
            if (count >= TOP_NUM) break;
        }
        if (lane == 0) count_sh = count;
    }
    __syncthreads();
    int count = count_sh;

    // ---- span-order bitonic sort (identical network; 2 elems/thread) ----
#pragma unroll
    for (int ii = 0; ii < 2; ++ii) {
        int i = t + ii * 512;
        unsigned long long k = 0xFFFFFFFFFFFFFFFFull;
        if (i < count) {
            int idx = (int)ord_g[sel_sh[i]];
            unsigned int key32 = (unsigned int)(starts[idx] * NUM_WORDS + ends[idx]);
            k = ((unsigned long long)key32 << 32) | (unsigned int)idx;
        }
        fkeys[i] = k;
    }
    __syncthreads();
    for (int size = 2; size <= 1024; size <<= 1) {
        for (int stride = size >> 1; stride > 0; stride >>= 1) {
#pragma unroll
            for (int ii = 0; ii < 2; ++ii) {
                int i = t + ii * 512;
                int ixj = i ^ stride;
                if (ixj > i) {
                    bool up = ((i & size) == 0);
                    unsigned long long a = fkeys[i], b = fkeys[ixj];
                    if ((a > b) == up) { fkeys[i] = b; fkeys[ixj] = a; }
                }
            }
            __syncthreads();
        }
    }
#pragma unroll
    for (int ii = 0; ii < 2; ++ii) {
        int i = t + ii * 512;
        if (i < TOP_NUM) {
            int fi = (i < count) ? (int)(fkeys[i] & 0xFFFFFFFFull)
                                 : (int)(fkeys[0] & 0xFFFFFFFFull);
            out[OUT_TOPIDX + i] = (float)fi;
            out[OUT_TSTART + i] = (float)starts[fi];
            out[OUT_TEND + i] = (float)ends[fi];
            out[OUT_TSCORE + i] = scores[fi];
            top_idx_ws[i] = fi;
        }
    }
}

// ---------------- gather top_span_emb rows directly from doc (exact fp32) ----------------
__global__ void gather_emb(const float* __restrict__ doc, const float* __restrict__ swe,
                           const float* __restrict__ attn_g, const int* __restrict__ starts,
                           const int* __restrict__ ends, const int* __restrict__ top_idx_ws,
                           float* __restrict__ out) {
    int r = blockIdx.x, t = threadIdx.x;
    int idx = top_idx_ws[r];
    int s = starts[idx], e = ends[idx];
    int wid = e - s;
    __shared__ float at[MSW];
    if (t < MSW) at[t] = attn_g[(size_t)idx * 32 + t];
    __syncthreads();
    float* dst = out + OUT_TEMB + (size_t)r * SPAN_DIM;
    if (t < 192) {
        int h4 = t * 4;
        f32x4 vs = *(const f32x4*)&doc[(size_t)s * HIDDEN + h4];
        f32x4 ve = *(const f32x4*)&doc[(size_t)e * HIDDEN + h4];
        f32x4 acc = {0.f, 0.f, 0.f, 0.f};
        for (int w = 0; w <= wid; ++w)
            acc += at[w] * *(const f32x4*)&doc[(size_t)(s + w) * HIDDEN + h4];
#pragma unroll
        for (int k = 0; k < 4; ++k) {
            dst[h4 + k] = vs[k];
            dst[HIDDEN + h4 + k] = ve[k];
            dst[2 * HIDDEN + FEAT + h4 + k] = acc[k];
        }
    }
    if (t < FEAT) dst[2 * HIDDEN + t] = swe[wid * FEAT + t];
}

extern "C" void kernel_launch(void* const* d_in, const int* in_sizes, int n_in,
                              void* d_out, int out_size, void* d_ws, size_t ws_size,
                              hipStream_t stream) {
    const float* mention_doc = (const float*)d_in[0];
    const float* span_width_emb = (const float*)d_in[1];
    const float* head_w = (const float*)d_in[2];
    const float* head_b = (const float*)d_in[3];
    const float* m_w1 = (const float*)d_in[4];
    const float* m_b1 = (const float*)d_in[5];
    const float* m_w2 = (const float*)d_in[6];
    const float* m_b2 = (const float*)d_in[7];
    const float* m_w3 = (const float*)d_in[8];
    const float* m_b3 = (const float*)d_in[9];
    const float* width_prior_emb = (const float*)d_in[10];
    const float* w_w1 = (const float*)d_in[11];
    const float* w_b1 = (const float*)d_in[12];
    const float* w_w2 = (const float*)d_in[13];
    const float* w_b2 = (const float*)d_in[14];
    const float* w_w3 = (const float*)d_in[15];
    const float* w_b3 = (const float*)d_in[16];
    const int* cand_starts = (const int*)d_in[17];
    const int* cand_ends = (const int*)d_in[18];

    char* w = (char*)d_ws;
    const size_t szH = (size_t)NUM_CAND * NP * 2;
    const size_t szW2 = (size_t)NP * KP2 * 2;
    const size_t szWc = (size_t)PNP * HIDDEN * 2;
    const size_t szD = (size_t)NUM_WORDS * HIDDEN * 2;
    char* p = w;
    unsigned short* h0 = (unsigned short*)p; p += szH;
    unsigned short* h1 = (unsigned short*)p; p += szH;
    unsigned short* w2t0 = (unsigned short*)p; p += szW2;
    unsigned short* w2t1 = (unsigned short*)p; p += szW2;
    unsigned short* Wc0 = (unsigned short*)p; p += szWc;
    unsigned short* Wc1 = (unsigned short*)p; p += szWc;
    unsigned short* d0 = (unsigned short*)p; p += szD;
    unsigned short* d1 = (unsigned short*)p; p += szD;
    float* P = (float*)p; p += (size_t)NUM_WORDS * PNP * 4;
    float* tw = (float*)p; p += (size_t)MSW * NP * 4;
    float* attn_g = (float*)p; p += (size_t)NUM_CAND * 32 * 4;
    float* partials = (float*)p; p += (size_t)NUM_CAND * 16 * 4;
    unsigned short* ord_g = (unsigned short*)p; p += (size_t)NUM_CAND * 2;
    unsigned int* se_g = (unsigned int*)p; p += (size_t)NUM_CAND * 4;
    unsigned short* sel_g = (unsigned short*)p; p += 2048;
    int* count_g = (int*)p; p += 128;
    float* head_s = (float*)p; p += NUM_WORDS * 4;
    float* width_s = (float*)p; p += 128;
    int* top_idx_ws = (int*)p; p += 4096;
    int* hist_g = (int*)p; p += NUM_WORDS * 4;
    int* perm_g = (int*)p; p += (size_t)NUM_CAND * 4;
    int* binoff_g = (int*)p; p += NUM_WORDS * 4;

    size_t need = (size_t)(p - w);
    if (ws_size < need) {
        fprintf(stderr, "kernel_launch: ws too small (%zu < %zu)\n", ws_size, need);
    }
    (void)sel_g; (void)count_g;

    float* out = (float*)d_out;

    head_kernel<<<NUM_WORDS / 4, 256, 0, stream>>>(mention_doc, head_w, head_b, head_s,
                                                   hist_g, d0, d1);
    width_kernel<<<MSW, 256, 0, stream>>>(width_prior_emb, w_w1, w_b1, w_w2, w_b2, w_w3, w_b3,
                                          width_s, span_width_emb, m_w1, tw);
    attn_kernel<<<NUM_CAND / 8, 256, 0, stream>>>(head_s, cand_starts, cand_ends, attn_g,
                                                  hist_g);
    convert_wc<<<dim3(12, 48), 256, 0, stream>>>(m_w1, Wc0, Wc1);
    convert_wt<<<dim3(16, 16), 256, 0, stream>>>(m_w2, w2t0, w2t1);
    perm_kernel<<<1, 256, 0, stream>>>(hist_g, cand_starts, perm_g, binoff_g);
    gemm3p<<<16 * 24, 256, 0, stream>>>(d0, d1, Wc0, Wc1, P);
    combine_kernel<<<NUM_WORDS, 256, 0, stream>>>(P, tw, attn_g, m_b1, cand_starts, cand_ends,
                                                  perm_g, binoff_g, hist_g, h0, h1);
    gemm3<<<512, 256, 0, stream>>>(h0, h1, w2t0, w2t1, m_b2, FFNN_DIM, KP2,
                                   m_w3, partials);
    score_final<<<NUM_CAND / 256, 256, 0, stream>>>(partials, m_b3, width_s, cand_starts,
                                                    cand_ends, out);
    rank_kernel<<<NUM_CAND / 32, 256, 0, stream>>>(out, cand_starts, cand_ends, ord_g, se_g);
    select_nms_post<<<1, 512, 0, stream>>>(se_g, ord_g, out, cand_starts, cand_ends,
                                           out, top_idx_ws);
    gather_emb<<<TOP_NUM, 256, 0, stream>>>(mention_doc, span_width_emb, attn_g, cand_starts,
                                            cand_ends, top_idx_ws, out);
}

// Round 13
// 740.207 us; speedup vs baseline: 1.0194x; 1.0194x over previous
//
#include <hip/hip_runtime.h>
#include <cstdio>
#include <cmath>

#define NUM_WORDS 2048
#define NUM_CAND 8192
#define HIDDEN 768
#define FEAT 20
#define FFNN_DIM 1000
#define SPAN_DIM 2324
#define TOP_NUM 819
#define MSW 30
#define KP2 1024   // FFNN padded to x32
#define NP 1024    // padded N
#define PNP 3072   // P matrix padded N (3 segments of 1024)

// d_out layout (floats): [scores 8192][top_idx 819][top_starts 819][top_ends 819]
//                        [top_span_emb 819*2324][top_scores 819]
#define OUT_TOPIDX   (NUM_CAND)
#define OUT_TSTART   (NUM_CAND + TOP_NUM)
#define OUT_TEND     (NUM_CAND + 2*TOP_NUM)
#define OUT_TEMB     (NUM_CAND + 3*TOP_NUM)
#define OUT_TSCORE   (NUM_CAND + 3*TOP_NUM + TOP_NUM*SPAN_DIM)

typedef short short8 __attribute__((ext_vector_type(8)));
typedef float f32x4 __attribute__((ext_vector_type(4)));
typedef unsigned short u16x4 __attribute__((ext_vector_type(4)));

__device__ __forceinline__ unsigned short bf16_rne(float x) {
    unsigned int u = __float_as_uint(x);
    unsigned int r = u + 0x7FFFu + ((u >> 16) & 1u);
    return (unsigned short)(r >> 16);
}
__device__ __forceinline__ float bf16_to_f(unsigned short h) {
    return __uint_as_float(((unsigned int)h) << 16);
}
// 2-way split: v = s0 + s1 + r, |r| <= 2^-16 |v| (r21-verified: absmax unchanged)
__device__ __forceinline__ void store_split2(unsigned short* p0, unsigned short* p1,
                                             size_t off, float v) {
    unsigned short h0 = bf16_rne(v);
    float r1 = v - bf16_to_f(h0);
    p0[off] = h0;
    p1[off] = bf16_rne(r1);
}

// async 16B global->LDS (gfx950 global_load_lds_dwordx4). LDS dest must be
// wave-uniform base + lane*16 -> linear LDS; swizzle applied to the GLOBAL source.
__device__ __forceinline__ void gl_lds16(const unsigned short* g, unsigned short* l) {
    __builtin_amdgcn_global_load_lds(
        (const __attribute__((address_space(1))) unsigned short*)g,
        (__attribute__((address_space(3))) unsigned short*)l, 16, 0, 0);
}

// ---------------- head scores + doc 2-split convert (r23 fusion; r27 vec convert) --------
// Convert half vectorized: f32x4 loads + u16x4 split stores (element-independent,
// identical per-element arithmetic -> bit-exact). Head reduction untouched.
__global__ void head_kernel(const float* __restrict__ doc, const float* __restrict__ hw,
                            const float* __restrict__ hb, float* __restrict__ out,
                            int* __restrict__ hist,
                            unsigned short* __restrict__ d0, unsigned short* __restrict__ d1) {
    int t = threadIdx.x;
    if (blockIdx.x == 0) {
        for (int i = t; i < NUM_WORDS; i += 256) hist[i] = 0;
    }
    {
        size_t base = (size_t)blockIdx.x * 4 * HIDDEN;
        const f32x4* doc4 = (const f32x4*)(doc + base);
        for (int i = t; i < 4 * HIDDEN / 4; i += 256) {
            f32x4 v = doc4[i];
            u16x4 q0, q1;
#pragma unroll
            for (int k = 0; k < 4; ++k) {
                unsigned short x0 = bf16_rne(v[k]);
                float r1 = v[k] - bf16_to_f(x0);
                q0[k] = x0; q1[k] = bf16_rne(r1);
            }
            *(u16x4*)&d0[base + i * 4] = q0;
            *(u16x4*)&d1[base + i * 4] = q1;
        }
    }
    int wave = t >> 6, lane = t & 63;
    int row = blockIdx.x * 4 + wave;
    if (row >= NUM_WORDS) return;
    float acc = 0.f;
    for (int h = lane; h < HIDDEN; h += 64) acc += doc[row * HIDDEN + h] * hw[h];
    for (int off = 32; off > 0; off >>= 1) acc += __shfl_down(acc, off);
    if (lane == 0) out[row] = acc + hb[0];
}

// ---------------- width prior ffnn [30,20]->[30] + T_w rows (r23 fusion) ----------------
__global__ void width_kernel(const float* __restrict__ x, const float* __restrict__ w1,
                             const float* __restrict__ b1, const float* __restrict__ w2,
                             const float* __restrict__ b2, const float* __restrict__ w3,
                             const float* __restrict__ b3, float* __restrict__ out,
                             const float* __restrict__ swe, const float* __restrict__ mw1,
                             float* __restrict__ tw) {
    __shared__ float xs[FEAT];
    __shared__ float h1s[FFNN_DIM];
    __shared__ float red[256];
    int r = blockIdx.x, t = threadIdx.x;
    if (t < FEAT) xs[t] = x[r * FEAT + t];
    __syncthreads();
    for (int j = t; j < FFNN_DIM; j += 256) {
        float acc = b1[j];
        for (int k = 0; k < FEAT; ++k) acc += xs[k] * w1[k * FFNN_DIM + j];
        h1s[j] = fmaxf(acc, 0.f);
    }
    __syncthreads();
    float partial = 0.f;
    for (int j = t; j < FFNN_DIM; j += 256) {
        float acc = b2[j];
        for (int k = 0; k < FFNN_DIM; ++k) acc += h1s[k] * w2[k * FFNN_DIM + j];
        partial += fmaxf(acc, 0.f) * w3[j];
    }
    red[t] = partial;
    __syncthreads();
    for (int s = 128; s > 0; s >>= 1) { if (t < s) red[t] += red[t + s]; __syncthreads(); }
    if (t == 0) out[r] = red[0] + b3[0];
    // T_w[r][1024] = span_width_emb[r] @ m_w1[1536:1556] (bit-identical to old tw_kernel)
    for (int n = t; n < NP; n += 256) {
        float acc = 0.f;
        if (n < FFNN_DIM) {
            for (int f = 0; f < FEAT; ++f)
                acc += swe[r * FEAT + f] * mw1[(size_t)(1536 + f) * FFNN_DIM + n];
        }
        tw[r * NP + n] = acc;
    }
}

// ---------------- attention weights per span: attn_g [8192][32] ----------------
// r25: 2 candidates per wave (32-lane segments); bit-exact vs the 64-wide form.
__global__ void attn_kernel(const float* __restrict__ head_s, const int* __restrict__ starts,
                            const int* __restrict__ ends, float* __restrict__ attn_g,
                            int* __restrict__ hist) {
    int c = blockIdx.x * 8 + (threadIdx.x >> 5);
    int w = threadIdx.x & 31;
    if (c >= NUM_CAND) return;
    int s = starts[c], e = ends[c];
    if (w == 0) atomicAdd(&hist[s], 1);
    int wid = e - s;
    float hsv = (w < MSW && w <= wid) ? head_s[s + w] : -INFINITY;
    float m = hsv;
    for (int off = 16; off > 0; off >>= 1) m = fmaxf(m, __shfl_down(m, off, 32));
    m = __shfl(m, 0, 32);
    float ex = (w < MSW && w <= wid) ? expf(hsv - m) : 0.f;
    float ssum = ex;
    for (int off = 16; off > 0; off >>= 1) ssum += __shfl_down(ssum, off, 32);
    ssum = __shfl(ssum, 0, 32);
    attn_g[c * 32 + w] = (w < MSW) ? (ex / ssum) : 0.f;
}

// ---------------- counting-sort permutation by start (scan + scatter, 1 block) ----------
// r27: reverted to the r11-verified form (r26 binned combine regressed 741->754).
__global__ __launch_bounds__(256) void perm_kernel(const int* __restrict__ hist,
                                                   const int* __restrict__ starts,
                                                   int* __restrict__ perm) {
    __shared__ int hoff[NUM_WORDS];
    __shared__ int wsum[4];
    int t = threadIdx.x, lane = t & 63, wv = t >> 6;
    int base = t * 8;
    int lh[8];
    int s0 = 0;
#pragma unroll
    for (int i = 0; i < 8; ++i) { lh[i] = hist[base + i]; s0 += lh[i]; }
    int sc = s0;
    for (int o = 1; o < 64; o <<= 1) { int v = __shfl_up(sc, o); if (lane >= o) sc += v; }
    if (lane == 63) wsum[wv] = sc;
    __syncthreads();
    int wbase = 0;
    for (int i = 0; i < wv; ++i) wbase += wsum[i];
    int run = wbase + sc - s0;  // exclusive prefix of this thread's 8 bins
#pragma unroll
    for (int i = 0; i < 8; ++i) { hoff[base + i] = run; run += lh[i]; }
    __syncthreads();
    for (int c = t; c < NUM_CAND; c += 256) {
        int pos = atomicAdd(&hoff[starts[c]], 1);
        perm[pos] = c;
    }
}

// ---------------- Wc convert via LDS tile-transpose: coalesced both sides --------------
__global__ __launch_bounds__(256) void convert_wc(const float* __restrict__ w1,
                                                  unsigned short* __restrict__ q0,
                                                  unsigned short* __restrict__ q1) {
    __shared__ float tile[64][65];
    int kbase = blockIdx.x << 6;            // 0..704 (12 tiles over 768)
    int n2base = blockIdx.y << 6;           // 0..3008 (48 tiles over 3072)
    int seg = n2base >> 10;
    int nbase = n2base & 1023;
    int row0 = (seg == 0) ? 0 : ((seg == 1) ? HIDDEN : 1556);
    int t = threadIdx.x;
    int c = t & 63, r0 = t >> 6;
    for (int rr = 0; rr < 64; rr += 4) {
        int r = rr + r0;
        int n = nbase + c;
        tile[r][c] = (n < FFNN_DIM) ? w1[(size_t)(row0 + kbase + r) * FFNN_DIM + n] : 0.f;
    }
    __syncthreads();
    int kl = t & 63;
    for (int rr = 0; rr < 64; rr += 4) {
        int nl = rr + r0;
        store_split2(q0, q1, (size_t)(n2base + nl) * HIDDEN + kbase + kl, tile[kl][nl]);
    }
}

// ---------------- w2 convert+transpose via LDS tiles: m_w2[1000][1000] -> [1024][1024] ---
__global__ __launch_bounds__(256) void convert_wt(const float* __restrict__ w,
                                                  unsigned short* __restrict__ q0,
                                                  unsigned short* __restrict__ q1) {
    __shared__ float tile[64][65];
    int kbase = blockIdx.x << 6;            // 16 tiles over 1024
    int nbase = blockIdx.y << 6;            // 16 tiles over 1024
    int t = threadIdx.x;
    int c = t & 63, r0 = t >> 6;
    for (int rr = 0; rr < 64; rr += 4) {
        int r = rr + r0;
        int k = kbase + r, n = nbase + c;
        tile[r][c] = (k < FFNN_DIM && n < FFNN_DIM) ? w[(size_t)k * FFNN_DIM + n] : 0.f;
    }
    __syncthreads();
    int kl = t & 63;
    for (int rr = 0; rr < 64; rr += 4) {
        int nl = rr + r0;
        store_split2(q0, q1, (size_t)(nbase + nl) * KP2 + kbase + kl, tile[kl][nl]);
    }
}

// Stage one 128x64-bf16 tile (16KB) async into LDS. r24: BK=64. LDS layout row-major
// [128][64]; LDS slot s (8 bf16) of row r holds global kblk s^(r&7).
__device__ __forceinline__ void stage_tile64(const unsigned short* __restrict__ src,
                                             unsigned short* lds, int base_row, int Kp,
                                             int k0, int t) {
#pragma unroll
    for (int qi = 0; qi < 4; ++qi) {
        int u = qi * 256 + t;           // 0..1023
        int row = u >> 3;
        int slot = u & 7;
        int kblk = slot ^ (row & 7);
        const unsigned short* g = src + (size_t)(base_row + row) * Kp + k0 + kblk * 8;
        gl_lds16(g, lds + u * 8);
    }
}

// ---------------- 2-split 3-product MFMA GEMM (BK=64), fp32 out: P = doc @ Wc ---------
__global__ __launch_bounds__(256, 2) void gemm3p(
    const unsigned short* __restrict__ A0, const unsigned short* __restrict__ A1,
    const unsigned short* __restrict__ B0, const unsigned short* __restrict__ B1,
    float* __restrict__ C) {
    __shared__ unsigned short As0[128 * 64], As1[128 * 64];
    __shared__ unsigned short Bs0[128 * 64], Bs1[128 * 64];
    int t = threadIdx.x;
    int bid = blockIdx.x;
    int g = bid & 7, rr = bid >> 3;         // xcd-chunk g: n_tiles {g, g+8, g+16}
    int bm = (rr & 15) << 7;
    int bn = (g + 8 * (rr >> 4)) << 7;
    int lane = t & 63, wv = t >> 6;
    int wm = (wv >> 1) * 64, wn = (wv & 1) * 64;
    int lr = lane & 15, qq = lane >> 4;

    f32x4 acc[4][4] = {};

    for (int k0 = 0; k0 < HIDDEN; k0 += 64) {
        stage_tile64(A0, As0, bm, HIDDEN, k0, t);
        stage_tile64(A1, As1, bm, HIDDEN, k0, t);
        stage_tile64(B0, Bs0, bn, HIDDEN, k0, t);
        stage_tile64(B1, Bs1, bn, HIDDEN, k0, t);
        __syncthreads();
        short8 a0[2][4], a1[2][4];
#pragma unroll
        for (int i = 0; i < 4; ++i) {
            int ra = (wm + i * 16 + lr) * 64;
#pragma unroll
            for (int h = 0; h < 2; ++h) {
                int sl = ((h * 4 + qq) ^ (lr & 7)) * 8;
                a0[h][i] = *(const short8*)&As0[ra + sl];
                a1[h][i] = *(const short8*)&As1[ra + sl];
            }
        }
#pragma unroll
        for (int j = 0; j < 4; ++j) {
            int rb = (wn + j * 16 + lr) * 64;
            short8 b0[2], b1[2];
#pragma unroll
            for (int h = 0; h < 2; ++h) {
                int sl = ((h * 4 + qq) ^ (lr & 7)) * 8;
                b0[h] = *(const short8*)&Bs0[rb + sl];
                b1[h] = *(const short8*)&Bs1[rb + sl];
            }
#pragma unroll
            for (int i = 0; i < 4; ++i) {
#pragma unroll
                for (int h = 0; h < 2; ++h) {
                    acc[i][j] = __builtin_amdgcn_mfma_f32_16x16x32_bf16(a1[h][i], b0[h], acc[i][j], 0, 0, 0);
                    acc[i][j] = __builtin_amdgcn_mfma_f32_16x16x32_bf16(a0[h][i], b1[h], acc[i][j], 0, 0, 0);
                    acc[i][j] = __builtin_amdgcn_mfma_f32_16x16x32_bf16(a0[h][i], b0[h], acc[i][j], 0, 0, 0);
                }
            }
        }
        __syncthreads();
    }
#pragma unroll
    for (int i = 0; i < 4; ++i)
#pragma unroll
        for (int j = 0; j < 4; ++j)
#pragma unroll
            for (int r = 0; r < 4; ++r) {
                int m = bm + wm + i * 16 + qq * 4 + r;
                int n = bn + wn + j * 16 + lr;
                C[(size_t)m * PNP + n] = acc[i][j][r];
            }
}

// ---------------- combine: h1[c] = relu(P_s[s] + P_e[e] + sum attn*P_a[s+w] + Tw + b1) ----
// r27: reverted to the r22/r25-verified form (8192 parallel blocks, XCD-chunked perm:
// block b -> perm[(b&7)*1024 + (b>>3)]; each XCD's L2 sees a contiguous ~256-start
// range of P rows). r26's binned variant regressed (serialized bins, lost TLP).
__global__ void combine_kernel(const float* __restrict__ P, const float* __restrict__ tw,
                               const float* __restrict__ attn_g, const float* __restrict__ b1,
                               const int* __restrict__ starts, const int* __restrict__ ends,
                               const int* __restrict__ perm,
                               unsigned short* __restrict__ h0, unsigned short* __restrict__ h1) {
    int pos = ((blockIdx.x & 7) << 10) | (blockIdx.x >> 3);
    int c = perm[pos];
    int t = threadIdx.x;
    int s = starts[c], e = ends[c];
    int wid = e - s;
    __shared__ float at[MSW];
    if (t < MSW) at[t] = attn_g[c * 32 + t];
    __syncthreads();
    int n0 = t * 4;
    size_t ho = (size_t)c * NP + n0;
    if (t < 250) {
        f32x4 acc = *(const f32x4*)&P[(size_t)s * PNP + n0];
        acc += *(const f32x4*)&P[(size_t)e * PNP + 1024 + n0];
        acc += *(const f32x4*)&tw[(size_t)wid * NP + n0];
        acc += *(const f32x4*)&b1[n0];
        const float* Pa = P + (size_t)s * PNP + 2048 + n0;
        for (int w = 0; w <= wid; ++w)
            acc += at[w] * *(const f32x4*)&Pa[(size_t)w * PNP];
        u16x4 q0, q1;
#pragma unroll
        for (int k = 0; k < 4; ++k) {
            float v = fmaxf(acc[k], 0.f);
            unsigned short x0 = bf16_rne(v);
            float r1 = v - bf16_to_f(x0);
            q0[k] = x0; q1[k] = bf16_rne(r1);
        }
        *(u16x4*)&h0[ho] = q0;
        *(u16x4*)&h1[ho] = q1;
    } else {
        u16x4 z = {0, 0, 0, 0};
        *(u16x4*)&h0[ho] = z;
        *(u16x4*)&h1[ho] = z;
    }
}

// ---------------- 2-split 3-product MFMA GEMM (BK=64, score fusion) ------------
__global__ __launch_bounds__(256, 2) void gemm3(
    const unsigned short* __restrict__ A0, const unsigned short* __restrict__ A1,
    const unsigned short* __restrict__ B0, const unsigned short* __restrict__ B1,
    const float* __restrict__ bias, int nreal, int Kp,
    const float* __restrict__ w3, float* __restrict__ partials) {
    __shared__ unsigned short As0[128 * 64], As1[128 * 64];
    __shared__ unsigned short Bs0[128 * 64], Bs1[128 * 64];
    int t = threadIdx.x;
    int bid = blockIdx.x;
    int bm = (bid >> 3) << 7;               // 64 M-tiles
    int bn = (bid & 7) << 7;                // 8 N-tiles; n ≡ bid (mod 8) -> per-XCD panel
    int lane = t & 63, wv = t >> 6;
    int wm = (wv >> 1) * 64, wn = (wv & 1) * 64;
    int lr = lane & 15, qq = lane >> 4;

    f32x4 acc[4][4] = {};

    for (int k0 = 0; k0 < Kp; k0 += 64) {
        stage_tile64(A0, As0, bm, Kp, k0, t);
        stage_tile64(A1, As1, bm, Kp, k0, t);
        stage_tile64(B0, Bs0, bn, Kp, k0, t);
        stage_tile64(B1, Bs1, bn, Kp, k0, t);
        __syncthreads();
        short8 a0[2][4], a1[2][4];
#pragma unroll
        for (int i = 0; i < 4; ++i) {
            int ra = (wm + i * 16 + lr) * 64;
#pragma unroll
            for (int h = 0; h < 2; ++h) {
                int sl = ((h * 4 + qq) ^ (lr & 7)) * 8;
                a0[h][i] = *(const short8*)&As0[ra + sl];
                a1[h][i] = *(const short8*)&As1[ra + sl];
            }
        }
#pragma unroll
        for (int j = 0; j < 4; ++j) {
            int rb = (wn + j * 16 + lr) * 64;
            short8 b0[2], b1[2];
#pragma unroll
            for (int h = 0; h < 2; ++h) {
                int sl = ((h * 4 + qq) ^ (lr & 7)) * 8;
                b0[h] = *(const short8*)&Bs0[rb + sl];
                b1[h] = *(const short8*)&Bs1[rb + sl];
            }
#pragma unroll
            for (int i = 0; i < 4; ++i) {
#pragma unroll
                for (int h = 0; h < 2; ++h) {
                    acc[i][j] = __builtin_amdgcn_mfma_f32_16x16x32_bf16(a1[h][i], b0[h], acc[i][j], 0, 0, 0);
                    acc[i][j] = __builtin_amdgcn_mfma_f32_16x16x32_bf16(a0[h][i], b1[h], acc[i][j], 0, 0, 0);
                    acc[i][j] = __builtin_amdgcn_mfma_f32_16x16x32_bf16(a0[h][i], b0[h], acc[i][j], 0, 0, 0);
                }
            }
        }
        __syncthreads();
    }

    int pid = ((bn >> 7) << 1) | (wn >> 6);  // 0..15
#pragma unroll
    for (int i = 0; i < 4; ++i)
#pragma unroll
        for (int r = 0; r < 4; ++r) {
            float p = 0.f;
#pragma unroll
            for (int j = 0; j < 4; ++j) {
                int n = bn + wn + j * 16 + lr;
                float v = acc[i][j][r] + (n < nreal ? bias[n] : 0.f);
                v = fmaxf(v, 0.f);
                p += v * (n < nreal ? w3[n] : 0.f);
            }
            p += __shfl_xor(p, 1);
            p += __shfl_xor(p, 2);
            p += __shfl_xor(p, 4);
            p += __shfl_xor(p, 8);
            if (lr == 0) {
                int m = bm + wm + i * 16 + qq * 4 + r;
                partials[(size_t)m * 16 + pid] = p;
            }
        }
}

// ---------------- deterministic score finalize ----------------
__global__ void score_final(const float* __restrict__ partials, const float* __restrict__ b3,
                            const float* __restrict__ width_s, const int* __restrict__ starts,
                            const int* __restrict__ ends, float* __restrict__ out) {
    int c = blockIdx.x * 256 + threadIdx.x;
    if (c >= NUM_CAND) return;
    float s = b3[0] + width_s[ends[c] - starts[c]];
#pragma unroll
    for (int p = 0; p < 16; ++p) s += partials[(size_t)c * 16 + p];
    out[c] = s;
}

// ---------------- exact counting rank-sort: 256 blocks ----------------
__global__ __launch_bounds__(256) void rank_kernel(const float* __restrict__ scores,
                                                   const int* __restrict__ starts,
                                                   const int* __restrict__ ends,
                                                   unsigned short* __restrict__ ord_g,
                                                   unsigned int* __restrict__ se_g) {
    __shared__ unsigned long long kk[NUM_CAND];  // 64 KB
    int t = threadIdx.x;
    for (int i = t; i < NUM_CAND; i += 256) {
        unsigned int b = __float_as_uint(scores[i]);
        unsigned int u = b ^ ((b & 0x80000000u) ? 0xFFFFFFFFu : 0x80000000u);
        unsigned int hi = ~u;
        kk[i] = ((unsigned long long)hi << 32) | (unsigned int)i;
    }
    __syncthreads();
    int c = blockIdx.x * 32 + (t >> 3);
    int seg = (t & 7) * 1024;
    int rot = (t & 7) * 2;
    unsigned long long mykey = kk[c];
    int cnt = 0;
    for (int ii = 0; ii < 1024; ++ii) {
        int i = seg + ((ii + rot) & 1023);
        cnt += (kk[i] < mykey) ? 1 : 0;
    }
    cnt += __shfl_xor(cnt, 1);
    cnt += __shfl_xor(cnt, 2);
    cnt += __shfl_xor(cnt, 4);
    if ((t & 7) == 0) {
        int idx = (int)(mykey & 0xFFFFFFFFull);
        int rank = cnt;
        ord_g[rank] = (unsigned short)idx;
        se_g[rank] = ((unsigned int)starts[idx] << 16) | (unsigned int)ends[idx];
    }
}

// ---------------- merged NMS + span-order sort + emit (r25) ----------------
// NMS decision path LOCKED at the r17-verified form (~292us; r13/r15/r18/r19/r20 all
// worse — cost is dependent-chain latency, structural). Do not restructure further.
__global__ __launch_bounds__(512, 1)
__attribute__((amdgpu_waves_per_eu(1, 2)))
void select_nms_post(const unsigned int* __restrict__ se_g,
                     const unsigned short* __restrict__ ord_g,
                     const float* __restrict__ scores,
                     const int* __restrict__ starts,
                     const int* __restrict__ ends,
                     float* __restrict__ out, int* __restrict__ top_idx_ws) {
    __shared__ unsigned int se_arr[NUM_CAND];    // 32 KB
    __shared__ unsigned int st[2 * NUM_WORDS];   // 16 KB
    __shared__ unsigned short sel_sh[1024];      //  2 KB
    __shared__ unsigned long long fkeys[1024];   //  8 KB
    __shared__ int count_sh;
    int t = threadIdx.x;

    {
        const uint4* src4 = (const uint4*)se_g;
        uint4* dst4 = (uint4*)se_arr;
        for (int i = t; i < NUM_CAND / 4; i += 512) dst4[i] = src4[i];
    }
    for (int i = t; i < 2 * NUM_WORDS; i += 512)
        st[i] = (i & 1) ? (unsigned int)NUM_WORDS : 0u;  // max_end+1=0, min_start=2048
    __syncthreads();

    if (t < 64) {
        int lane = t;
        const unsigned long long* stp = (const unsigned long long*)st;
        int count = 0;
        for (int c = 0; c < NUM_CAND / 64; ++c) {
            int ib = c * 64;
            unsigned int sev = se_arr[ib + lane];
            int s = (int)(sev >> 16), e = (int)(sev & 0xFFFFu);
            const unsigned long long* bp = stp + s;
            unsigned long long v[MSW];
#pragma unroll
            for (int w = 0; w < MSW; ++w) v[w] = bp[w];
            int me = (int)(unsigned int)v[0] - 1;
            bool crossedA = (s < e) && ((int)(unsigned int)(v[0] >> 32) < s);
            bool crossedB = false;
#pragma unroll
            for (int w = 1; w < MSW; ++w) {
                int j = s + w;
                bool in = (j <= e);
                int mej = (int)(unsigned int)v[w] - 1;
                int msj = (int)(unsigned int)(v[w] >> 32);
                bool hit = in && ((mej > e) || ((j < e) && (msj < s)));
                if (w & 1) crossedA = crossedA || hit;
                else       crossedB = crossedB || hit;
            }
            bool crossed = crossedA || crossedB;
            bool spec = !crossed && (me != e);

            // serial resolve — decision loop identical to the r2..r17-verified form
            int cbefore = count;
            unsigned long long window = ~0ull;
            unsigned int pend = 0u;
            int rk = 0, lcnt = 0;
            while (true) {
                unsigned long long b = __ballot(spec) & window;
                if (b == 0ull) break;
                int f = __ffsll((unsigned long long)b) - 1;
                unsigned int sef = __builtin_amdgcn_readlane(sev, (unsigned int)f);
                int sf = (int)(sef >> 16), ef = (int)(sef & 0xFFFFu);
                bool mine = (lane == lcnt);
                pend = mine ? sef : pend;
                rk = mine ? (ib + f) : rk;
                lcnt++;
                count++;
                if (count >= TOP_NUM) break;
                window &= (f >= 63) ? 0ull : (~0ull << (f + 1));
                if (lane > f) {
                    if (s == sf) me = max(me, ef);
                    crossed = crossed || ((s < sf) && (sf <= e) && (ef > e))
                                      || ((sf < s) && (s <= ef) && (ef < e));
                    spec = !crossed && (me != e);
                }
            }
            if (lane < lcnt) {
                int sf = (int)(pend >> 16), ef = (int)(pend & 0xFFFFu);
                sel_sh[cbefore + lane] = (unsigned short)rk;
                atomicMax(&st[2 * sf], (unsigned int)(ef + 1));
                atomicMin(&st[2 * ef + 1], (unsigned int)sf);
            }
            if (count >= TOP_NUM) break;
        }
        if (lane == 0) count_sh = count;
    }
    __syncthreads();
    int count = count_sh;

    // ---- span-order bitonic sort (identical network; 2 elems/thread) ----
#pragma unroll
    for (int ii = 0; ii < 2; ++ii) {
        int i = t + ii * 512;
        unsigned long long k = 0xFFFFFFFFFFFFFFFFull;
        if (i < count) {
            int idx = (int)ord_g[sel_sh[i]];
            unsigned int key32 = (unsigned int)(starts[idx] * NUM_WORDS + ends[idx]);
            k = ((unsigned long long)key32 << 32) | (unsigned int)idx;
        }
        fkeys[i] = k;
    }
    __syncthreads();
    for (int size = 2; size <= 1024; size <<= 1) {
        for (int stride = size >> 1; stride > 0; stride >>= 1) {
#pragma unroll
            for (int ii = 0; ii < 2; ++ii) {
                int i = t + ii * 512;
                int ixj = i ^ stride;
                if (ixj > i) {
                    bool up = ((i & size) == 0);
                    unsigned long long a = fkeys[i], b = fkeys[ixj];
                    if ((a > b) == up) { fkeys[i] = b; fkeys[ixj] = a; }
                }
            }
            __syncthreads();
        }
    }
#pragma unroll
    for (int ii = 0; ii < 2; ++ii) {
        int i = t + ii * 512;
        if (i < TOP_NUM) {
            int fi = (i < count) ? (int)(fkeys[i] & 0xFFFFFFFFull)
                                 : (int)(fkeys[0] & 0xFFFFFFFFull);
            out[OUT_TOPIDX + i] = (float)fi;
            out[OUT_TSTART + i] = (float)starts[fi];
            out[OUT_TEND + i] = (float)ends[fi];
            out[OUT_TSCORE + i] = scores[fi];
            top_idx_ws[i] = fi;
        }
    }
}

// ---------------- gather top_span_emb rows directly from doc (exact fp32) ----------------
__global__ void gather_emb(const float* __restrict__ doc, const float* __restrict__ swe,
                           const float* __restrict__ attn_g, const int* __restrict__ starts,
                           const int* __restrict__ ends, const int* __restrict__ top_idx_ws,
                           float* __restrict__ out) {
    int r = blockIdx.x, t = threadIdx.x;
    int idx = top_idx_ws[r];
    int s = starts[idx], e = ends[idx];
    int wid = e - s;
    __shared__ float at[MSW];
    if (t < MSW) at[t] = attn_g[(size_t)idx * 32 + t];
    __syncthreads();
    float* dst = out + OUT_TEMB + (size_t)r * SPAN_DIM;
    if (t < 192) {
        int h4 = t * 4;
        f32x4 vs = *(const f32x4*)&doc[(size_t)s * HIDDEN + h4];
        f32x4 ve = *(const f32x4*)&doc[(size_t)e * HIDDEN + h4];
        f32x4 acc = {0.f, 0.f, 0.f, 0.f};
        for (int w = 0; w <= wid; ++w)
            acc += at[w] * *(const f32x4*)&doc[(size_t)(s + w) * HIDDEN + h4];
#pragma unroll
        for (int k = 0; k < 4; ++k) {
            dst[h4 + k] = vs[k];
            dst[HIDDEN + h4 + k] = ve[k];
            dst[2 * HIDDEN + FEAT + h4 + k] = acc[k];
        }
    }
    if (t < FEAT) dst[2 * HIDDEN + t] = swe[wid * FEAT + t];
}

extern "C" void kernel_launch(void* const* d_in, const int* in_sizes, int n_in,
                              void* d_out, int out_size, void* d_ws, size_t ws_size,
                              hipStream_t stream) {
    const float* mention_doc = (const float*)d_in[0];
    const float* span_width_emb = (const float*)d_in[1];
    const float* head_w = (const float*)d_in[2];
    const float* head_b = (const float*)d_in[3];
    const float* m_w1 = (const float*)d_in[4];
    const float* m_b1 = (const float*)d_in[5];
    const float* m_w2 = (const float*)d_in[6];
    const float* m_b2 = (const float*)d_in[7];
    const float* m_w3 = (const float*)d_in[8];
    const float* m_b3 = (const float*)d_in[9];
    const float* width_prior_emb = (const float*)d_in[10];
    const float* w_w1 = (const float*)d_in[11];
    const float* w_b1 = (const float*)d_in[12];
    const float* w_w2 = (const float*)d_in[13];
    const float* w_b2 = (const float*)d_in[14];
    const float* w_w3 = (const float*)d_in[15];
    const float* w_b3 = (const float*)d_in[16];
    const int* cand_starts = (const int*)d_in[17];
    const int* cand_ends = (const int*)d_in[18];

    char* w = (char*)d_ws;
    const size_t szH = (size_t)NUM_CAND * NP * 2;
    const size_t szW2 = (size_t)NP * KP2 * 2;
    const size_t szWc = (size_t)PNP * HIDDEN * 2;
    const size_t szD = (size_t)NUM_WORDS * HIDDEN * 2;
    char* p = w;
    unsigned short* h0 = (unsigned short*)p; p += szH;
    unsigned short* h1 = (unsigned short*)p; p += szH;
    unsigned short* w2t0 = (unsigned short*)p; p += szW2;
    unsigned short* w2t1 = (unsigned short*)p; p += szW2;
    unsigned short* Wc0 = (unsigned short*)p; p += szWc;
    unsigned short* Wc1 = (unsigned short*)p; p += szWc;
    unsigned short* d0 = (unsigned short*)p; p += szD;
    unsigned short* d1 = (unsigned short*)p; p += szD;
    float* P = (float*)p; p += (size_t)NUM_WORDS * PNP * 4;
    float* tw = (float*)p; p += (size_t)MSW * NP * 4;
    float* attn_g = (float*)p; p += (size_t)NUM_CAND * 32 * 4;
    float* partials = (float*)p; p += (size_t)NUM_CAND * 16 * 4;
    unsigned short* ord_g = (unsigned short*)p; p += (size_t)NUM_CAND * 2;
    unsigned int* se_g = (unsigned int*)p; p += (size_t)NUM_CAND * 4;
    unsigned short* sel_g = (unsigned short*)p; p += 2048;
    int* count_g = (int*)p; p += 128;
    float* head_s = (float*)p; p += NUM_WORDS * 4;
    float* width_s = (float*)p; p += 128;
    int* top_idx_ws = (int*)p; p += 4096;
    int* hist_g = (int*)p; p += NUM_WORDS * 4;
    int* perm_g = (int*)p; p += (size_t)NUM_CAND * 4;

    size_t need = (size_t)(p - w);
    if (ws_size < need) {
        fprintf(stderr, "kernel_launch: ws too small (%zu < %zu)\n", ws_size, need);
    }
    (void)sel_g; (void)count_g;

    float* out = (float*)d_out;

    head_kernel<<<NUM_WORDS / 4, 256, 0, stream>>>(mention_doc, head_w, head_b, head_s,
                                                   hist_g, d0, d1);
    width_kernel<<<MSW, 256, 0, stream>>>(width_prior_emb, w_w1, w_b1, w_w2, w_b2, w_w3, w_b3,
                                          width_s, span_width_emb, m_w1, tw);
    attn_kernel<<<NUM_CAND / 8, 256, 0, stream>>>(head_s, cand_starts, cand_ends, attn_g,
                                                  hist_g);
    convert_wc<<<dim3(12, 48), 256, 0, stream>>>(m_w1, Wc0, Wc1);
    convert_wt<<<dim3(16, 16), 256, 0, stream>>>(m_w2, w2t0, w2t1);
    perm_kernel<<<1, 256, 0, stream>>>(hist_g, cand_starts, perm_g);
    gemm3p<<<16 * 24, 256, 0, stream>>>(d0, d1, Wc0, Wc1, P);
    combine_kernel<<<NUM_CAND, 256, 0, stream>>>(P, tw, attn_g, m_b1, cand_starts, cand_ends,
                                                 perm_g, h0, h1);
    gemm3<<<512, 256, 0, stream>>>(h0, h1, w2t0, w2t1, m_b2, FFNN_DIM, KP2,
                                   m_w3, partials);
    score_final<<<NUM_CAND / 256, 256, 0, stream>>>(partials, m_b3, width_s, cand_starts,
                                                    cand_ends, out);
    rank_kernel<<<NUM_CAND / 32, 256, 0, stream>>>(out, cand_starts, cand_ends, ord_g, se_g);
    select_nms_post<<<1, 512, 0, stream>>>(se_g, ord_g, out, cand_starts, cand_ends,
                                           out, top_idx_ws);
    gather_emb<<<TOP_NUM, 256, 0, stream>>>(mention_doc, span_width_emb, attn_g, cand_starts,
                                            cand_ends, top_idx_ws, out);
}